// Round 6
// baseline (219.110 us; speedup 1.0000x reference)
//
#include <hip/hip_runtime.h>

// B=4, C=256, H=W=64, O=256, K=3, PAD=2, DIL=2; offset conv: 18ch 3x3 p1 d1.
// R6: deform restructured to ONE barrier per chunk (colf double-buffered,
// MFMA(i) || sample(i+1) || stage(i+2) between barriers), 8x4 px tiles ->
// 512 blocks = 2 blocks/CU for cross-block latency hiding. Offset conv split
// over c (atomic partials, 2 blocks/CU); bias+clip back in deform phase 0
// (R3-verified formula). Cols bf16 conversion: truncation.

typedef __attribute__((ext_vector_type(8))) short short8;
typedef __attribute__((ext_vector_type(4))) float floatx4;

__device__ inline unsigned short f2bf(float f) {  // RNE fp32 -> bf16 bits
  unsigned int u = __float_as_uint(f);
  u += 0x7fff + ((u >> 16) & 1);
  return (unsigned short)(u >> 16);
}
__device__ inline float bfpair_lo(unsigned int u) {
  return __uint_as_float(u << 16);
}
__device__ inline float bfpair_hi(unsigned int u) {
  return __uint_as_float(u & 0xffff0000u);
}

// ---------------------------------------------------------------------------
// prep: wfrag (deform weights, R3-verified layout):
//   [ci=36][mt=16][kt=2][lane=64][j=8], val = w[o=mt*16+(lane&15)]
//   [k=ci*64+kt*32+(lane>>4)*8+j], k = c*9+n.
// wfragA (offset weights, zero-padded to M=32): [kse=72][mt=2][lane=64][j=8]
// ---------------------------------------------------------------------------
__global__ __launch_bounds__(256) void prep_kernel(
    const float* __restrict__ dw, const float* __restrict__ ow,
    unsigned short* __restrict__ wfrag, unsigned short* __restrict__ wfragA) {
  int idx = blockIdx.x * 256 + threadIdx.x;
  if (idx < 73728) {
    int ci = idx >> 11;
    int rem = idx & 2047;
    int mt = rem >> 7;
    int rem2 = rem & 127;
    int kt = rem2 >> 6, lane = rem2 & 63;
    int o = mt * 16 + (lane & 15);
    int kb = ci * 64 + kt * 32 + (lane >> 4) * 8;
    short8 v;
#pragma unroll
    for (int j = 0; j < 8; ++j) v[j] = (short)f2bf(dw[o * 2304 + kb + j]);
    *((short8*)wfrag + idx) = v;
  } else {
    int e = idx - 73728;
    if (e < 9216) {
      int lane = e & 63;
      int mt = (e >> 6) & 1;
      int kse = e >> 7;
      int o = mt * 16 + (lane & 15);
      short8 v;
      if (o < 18) {
        const float* src = ow + (size_t)o * 2304 + kse * 32 + (lane >> 4) * 8;
#pragma unroll
        for (int j = 0; j < 8; ++j) v[j] = (short)f2bf(src[j]);
      } else {
        v = (short8)0;
      }
      *((short8*)wfragA + e) = v;
    }
  }
}

// ---------------------------------------------------------------------------
// Offset conv via MFMA, c-split: grid (64 tiles, 4 b, 2 cg); each block does
// 128 channels (4 super-chunks of 32 c) and atomicAdds fp32 partials to
// off_buf (zeroed each launch). No bias/clip here (deform phase 0 does it).
// ---------------------------------------------------------------------------
__global__ __launch_bounds__(256) void offset_conv_mfma(
    const float* __restrict__ x, const unsigned short* __restrict__ wfragA,
    float* __restrict__ off_buf) {
  int tid = threadIdx.x;
  int b = blockIdx.y, tile = blockIdx.x, cg = blockIdx.z;
  int h0 = (tile >> 3) * 8, w0 = (tile & 7) * 8;
  int lane = tid & 63, wv = tid >> 6;

  __shared__ unsigned int s_xp[2][2560];  // [buf][cp*160 + ry*16 + rx]

  floatx4 acc[2];
  acc[0] = (floatx4)(0.f);
  acc[1] = (floatx4)(0.f);

  const float* xb = x + (size_t)b * 256 * 4096;

  // stage sc = cg*4
  for (int e = tid; e < 2560; e += 256) {
    int cp = e / 160;
    int pos = e - cp * 160;
    int ry = pos >> 4, rx = pos & 15;
    int gy = h0 - 1 + ry, gx = w0 - 1 + rx;
    bool ok = (gy >= 0 && gy < 64 && gx >= 0 && gx < 64);
    const float* p0 = xb + (size_t)(cg * 128 + cp * 2) * 4096;
    float v0 = ok ? p0[gy * 64 + gx] : 0.f;
    float v1 = ok ? p0[4096 + gy * 64 + gx] : 0.f;
    s_xp[0][e] = (unsigned int)f2bf(v0) | ((unsigned int)f2bf(v1) << 16);
  }
  __syncthreads();

  int p = wv * 16 + (lane & 15);
  int ly = p >> 3, lx = p & 7;
  int kq = lane >> 4;

  const short8* wA = (const short8*)wfragA;
  int ksf0 = cg * 36;
  short8 a0 = wA[(ksf0 * 2 + 0) * 64 + lane];
  short8 a1 = wA[(ksf0 * 2 + 1) * 64 + lane];

  for (int scl = 0; scl < 4; ++scl) {
    int sc = cg * 4 + scl;
    int buf = scl & 1;
    bool on = (scl + 1 < 4);
    float q0[10], q1[10];
#pragma unroll
    for (int pp = 0; pp < 10; ++pp) {
      q0[pp] = 0.f;
      q1[pp] = 0.f;
      if (on) {
        int e = tid + pp * 256;
        int cp = e / 160;
        int pos = e - cp * 160;
        int ry = pos >> 4, rx = pos & 15;
        int gy = h0 - 1 + ry, gx = w0 - 1 + rx;
        bool ok = (gy >= 0 && gy < 64 && gx >= 0 && gx < 64);
        if (ok) {
          const float* p0 = xb + (size_t)((sc + 1) * 32 + cp * 2) * 4096;
          q0[pp] = p0[gy * 64 + gx];
          q1[pp] = p0[4096 + gy * 64 + gx];
        }
      }
    }
    for (int ks = 0; ks < 9; ++ks) {
      int ksf = sc * 9 + ks;
      short8 na0, na1;
      if (ksf + 1 < 72) {
        na0 = wA[((ksf + 1) * 2 + 0) * 64 + lane];
        na1 = wA[((ksf + 1) * 2 + 1) * 64 + lane];
      }
      int kbase = ks * 32 + kq * 8;
      unsigned int uu[8];
#pragma unroll
      for (int j = 0; j < 8; ++j) {
        int kl = kbase + j;
        int cl = (int)((unsigned)kl / 9u);
        int t = kl - cl * 9;
        int ty = t / 3, tx = t - ty * 3;
        uu[j] = s_xp[buf][(cl >> 1) * 160 + (ly + ty) * 16 + (lx + tx)];
      }
      short8 bfr;
#pragma unroll
      for (int j = 0; j < 8; ++j) {
        int kl = kbase + j;
        int cl = (int)((unsigned)kl / 9u);
        bfr[j] = (short)((cl & 1) ? (uu[j] >> 16) : (uu[j] & 0xffff));
      }
      acc[0] =
          __builtin_amdgcn_mfma_f32_16x16x32_bf16(a0, bfr, acc[0], 0, 0, 0);
      acc[1] =
          __builtin_amdgcn_mfma_f32_16x16x32_bf16(a1, bfr, acc[1], 0, 0, 0);
      a0 = na0;
      a1 = na1;
    }
    if (on) {
#pragma unroll
      for (int pp = 0; pp < 10; ++pp) {
        int e = tid + pp * 256;
        s_xp[buf ^ 1][e] =
            (unsigned int)f2bf(q0[pp]) | ((unsigned int)f2bf(q1[pp]) << 16);
      }
    }
    __syncthreads();
  }

  // epilogue: col=lane&15 (px), row=quad*4+r (o); atomic partial sums
  int quad = lane >> 4, col = lane & 15;
  int pp2 = wv * 16 + col;
  int hh = h0 + (pp2 >> 3), ww = w0 + (pp2 & 7);
#pragma unroll
  for (int mt = 0; mt < 2; ++mt)
#pragma unroll
    for (int r = 0; r < 4; ++r) {
      int o = mt * 16 + quad * 4 + r;
      if (o < 18)
        atomicAdd(&off_buf[(((size_t)b * 18 + o) * 64 + hh) * 64 + ww],
                  acc[mt][r]);
    }
}

// ---------------------------------------------------------------------------
// Sampler for one 64-k chunk: 288 (n,px) items, bf16-pair corner reads from
// sxp (15 rows x stride 12), bilinear, truncate-to-bf16 scatter into colf in
// B-fragment order. Index math identical to R3/R4/R5-verified kernels.
// ---------------------------------------------------------------------------
__device__ __forceinline__ void sample_chunk(
    const unsigned int* __restrict__ sxp, unsigned short* __restrict__ colf,
    int k0, int tid, const float (*sw4)[32][4], const int (*scoff)[32]) {
  int cp_lo = (k0 / 9) >> 1;
  for (int e = tid; e < 288; e += 256) {
    int n = e >> 5, pe = e & 31;
    float4 wq = *(const float4*)&sw4[n][pe][0];
    int coff = scoff[n][pe];
    int nt_self = pe >> 4;
    int cs = (k0 - n + 8) / 9;
    int ce = (k0 + 72 - n) / 9;
    int cp_s = cs >> 1;
    int ncp = ((ce - 1) >> 1) - cp_s + 1;  // <= 5
    int base = (cp_s - cp_lo) * 180 + coff;
    unsigned int ug[5][4];
#pragma unroll
    for (int q = 0; q < 5; ++q) {
      if (q < ncp) {
        const unsigned int* pl = sxp + base + q * 180;
        ug[q][0] = pl[0];
        ug[q][1] = pl[1];
        ug[q][2] = pl[12];
        ug[q][3] = pl[13];
      }
    }
#pragma unroll
    for (int q = 0; q < 5; ++q) {
      if (q < ncp) {
        int c_even = (cp_s + q) * 2;
#pragma unroll
        for (int half = 0; half < 2; ++half) {
          int c = c_even + half;
          if (c >= cs && c < ce) {
            float v00, v01, v10, v11;
            if (half) {
              v00 = bfpair_hi(ug[q][0]);
              v01 = bfpair_hi(ug[q][1]);
              v10 = bfpair_hi(ug[q][2]);
              v11 = bfpair_hi(ug[q][3]);
            } else {
              v00 = bfpair_lo(ug[q][0]);
              v01 = bfpair_lo(ug[q][1]);
              v10 = bfpair_lo(ug[q][2]);
              v11 = bfpair_lo(ug[q][3]);
            }
            float v = wq.x * v00 + wq.y * v01 + wq.z * v10 + wq.w * v11;
            int kl = c * 9 + n - k0;  // 0..63
            int kt = kl >> 5, qk = (kl >> 3) & 3, j = kl & 7;
            colf[((nt_self * 2 + kt) * 64 + ((pe & 15) | (qk << 4))) * 8 + j] =
                (unsigned short)(__float_as_uint(v) >> 16);
          }
        }
      }
    }
  }
}

// ---------------------------------------------------------------------------
// Fused bilinear sample + bf16 MFMA GEMM. 8x4 px tile, 256 o, 256 thr
// (4 waves, wave = 64-o quarter). Grid (128,4) = 512 blocks = 2/CU.
// One barrier per chunk: MFMA(ci) || sample(ci+1) || stage(ci+2).
// ---------------------------------------------------------------------------
__global__ __launch_bounds__(256, 2) void deform_kernel(
    const float* __restrict__ x, const float* __restrict__ off_buf,
    const float* __restrict__ obias, const unsigned short* __restrict__ wfrag,
    const float* __restrict__ bias, float* __restrict__ out) {
  int tid = threadIdx.x;
  int b = blockIdx.y, tile = blockIdx.x;
  int h0 = (tile >> 4) * 8, w0 = (tile & 15) * 4;
  int lane = tid & 63, wv = tid >> 6;
  int oq = wv;

  __shared__ unsigned int s_xp[2][6 * 180];  // [buf][slot*180 + ry*12 + rx]
  __shared__ __align__(16) unsigned short s_colf[2][2048];
  __shared__ __align__(16) float s_w4[9][32][4];
  __shared__ int s_coff[9][32];

  // phase 0 (R3-verified): bias + clip fused here; off_buf holds raw sums.
  for (int e = tid; e < 288; e += 256) {
    int n = e >> 5, pe = e & 31;
    int hy = h0 + (pe >> 2), wx = w0 + (pe & 3);
    float dy =
        off_buf[(((size_t)b * 18 + 2 * n) * 64 + hy) * 64 + wx] + obias[2 * n];
    float dx = off_buf[(((size_t)b * 18 + 2 * n + 1) * 64 + hy) * 64 + wx] +
               obias[2 * n + 1];
    dy = fminf(fmaxf(dy, -1.f), 1.f);
    dx = fminf(fmaxf(dx, -1.f), 1.f);
    float fy = dy + (float)(hy - 2 + (n / 3) * 2);
    float fx = dx + (float)(wx - 2 + (n % 3) * 2);
    float y0f = floorf(fy), x0f = floorf(fx);
    float wy1 = fy - y0f, wx1 = fx - x0f;
    float wy0 = 1.f - wy1, wx0 = 1.f - wx1;
    s_coff[n][pe] = ((int)y0f - (h0 - 3)) * 12 + ((int)x0f - (w0 - 3));
    s_w4[n][pe][0] = wy0 * wx0;
    s_w4[n][pe][1] = wy0 * wx1;
    s_w4[n][pe][2] = wy1 * wx0;
    s_w4[n][pe][3] = wy1 * wx1;
  }

  const float* xb = x + (size_t)b * 256 * 4096;
  // stage chunk 0 direct (c 0..7 -> 4 slots x 180)
  for (int e2 = tid; e2 < 720; e2 += 256) {
    int sl = e2 / 180, pos = e2 - sl * 180;
    int ry = pos / 12, rx = pos - ry * 12;
    int gy = h0 - 3 + ry, gx = w0 - 3 + rx;
    bool ok = (rx < 11 && gy >= 0 && gy < 64 && gx >= 0 && gx < 64);
    const float* p0 = xb + (size_t)(sl * 2) * 4096;
    float v0 = ok ? p0[gy * 64 + gx] : 0.f;
    float v1 = ok ? p0[4096 + gy * 64 + gx] : 0.f;
    s_xp[0][e2] = (unsigned int)f2bf(v0) | ((unsigned int)f2bf(v1) << 16);
  }
  __syncthreads();

  // prologue: sample chunk 0 -> colf[0]; stage chunk 1 -> xp[1]
  sample_chunk(s_xp[0], s_colf[0], 0, tid, s_w4, s_coff);
  {
    // chunk 1: k0=64 -> c 7..14 -> pairs 3..7 (5 slots)
    float pr0[4], pr1[4];
#pragma unroll
    for (int pp = 0; pp < 4; ++pp) {
      int e2 = tid + pp * 256;
      pr0[pp] = 0.f;
      pr1[pp] = 0.f;
      if (e2 < 900) {
        int sl = e2 / 180, pos = e2 - sl * 180;
        int ry = pos / 12, rx = pos - ry * 12;
        int gy = h0 - 3 + ry, gx = w0 - 3 + rx;
        bool ok = (rx < 11 && gy >= 0 && gy < 64 && gx >= 0 && gx < 64);
        if (ok) {
          const float* p0 = xb + (size_t)((3 + sl) * 2) * 4096;
          pr0[pp] = p0[gy * 64 + gx];
          pr1[pp] = p0[4096 + gy * 64 + gx];
        }
      }
    }
#pragma unroll
    for (int pp = 0; pp < 4; ++pp) {
      int e2 = tid + pp * 256;
      if (e2 < 900)
        s_xp[1][e2] =
            (unsigned int)f2bf(pr0[pp]) | ((unsigned int)f2bf(pr1[pp]) << 16);
    }
  }
  __syncthreads();

  floatx4 acc[4][2];
#pragma unroll
  for (int i = 0; i < 4; ++i)
#pragma unroll
    for (int j = 0; j < 2; ++j) acc[i][j] = (floatx4)(0.f);

  for (int ci = 0; ci < 36; ++ci) {
    int k0 = ci * 64;
    // A-frags for chunk ci (global/L2; consumed below after sampling)
    short8 areg[2][4];
    const short8* wg = (const short8*)wfrag + (size_t)ci * 2048;
#pragma unroll
    for (int kt = 0; kt < 2; ++kt)
#pragma unroll
      for (int mi = 0; mi < 4; ++mi)
        areg[kt][mi] = wg[((oq * 4 + mi) * 2 + kt) * 64 + lane];

    // staging prefetch for chunk ci+2 into regs
    int tot2 = 0, cpl2 = 0;
    if (ci + 2 < 36) {
      int k0n = (ci + 2) * 64;
      int c_lo = k0n / 9, c_hi = (k0n + 63) / 9;
      cpl2 = c_lo >> 1;
      tot2 = ((c_hi >> 1) - cpl2 + 1) * 180;
    }
    float pr0[4], pr1[4];
#pragma unroll
    for (int pp = 0; pp < 4; ++pp) {
      int e2 = tid + pp * 256;
      pr0[pp] = 0.f;
      pr1[pp] = 0.f;
      if (e2 < tot2) {
        int sl = e2 / 180, pos = e2 - sl * 180;
        int ry = pos / 12, rx = pos - ry * 12;
        int gy = h0 - 3 + ry, gx = w0 - 3 + rx;
        bool ok = (rx < 11 && gy >= 0 && gy < 64 && gx >= 0 && gx < 64);
        if (ok) {
          const float* p0 = xb + (size_t)((cpl2 + sl) * 2) * 4096;
          pr0[pp] = p0[gy * 64 + gx];
          pr1[pp] = p0[4096 + gy * 64 + gx];
        }
      }
    }

    // sample chunk ci+1 from xp[(ci+1)&1] -> colf[(ci+1)&1]
    if (ci + 1 < 36)
      sample_chunk(s_xp[(ci + 1) & 1], s_colf[(ci + 1) & 1], k0 + 64, tid,
                   s_w4, s_coff);

    // MFMA chunk ci from colf[ci&1]
    const unsigned short* cf = s_colf[ci & 1];
#pragma unroll
    for (int kt = 0; kt < 2; ++kt) {
      short8 bfr[2];
#pragma unroll
      for (int tn = 0; tn < 2; ++tn)
        bfr[tn] = *(const short8*)&cf[((tn * 2 + kt) * 64 + lane) * 8];
#pragma unroll
      for (int mi = 0; mi < 4; ++mi)
#pragma unroll
        for (int tn = 0; tn < 2; ++tn)
          acc[mi][tn] = __builtin_amdgcn_mfma_f32_16x16x32_bf16(
              areg[kt][mi], bfr[tn], acc[mi][tn], 0, 0, 0);
    }

    // commit staged regs -> xp[ci&1] (holds chunk ci+2)
#pragma unroll
    for (int pp = 0; pp < 4; ++pp) {
      int e2 = tid + pp * 256;
      if (e2 < tot2)
        s_xp[ci & 1][e2] =
            (unsigned int)f2bf(pr0[pp]) | ((unsigned int)f2bf(pr1[pp]) << 16);
    }
    __syncthreads();
  }

  // epilogue: C/D col=lane&15 (px within n-tile), row=quad*4+r (o)
  int quad = lane >> 4, col = lane & 15;
#pragma unroll
  for (int mi = 0; mi < 4; ++mi)
#pragma unroll
    for (int tn = 0; tn < 2; ++tn) {
      int pxo = tn * 16 + col;
      int h = h0 + (pxo >> 2), w = w0 + (pxo & 3);
#pragma unroll
      for (int r = 0; r < 4; ++r) {
        int o = oq * 64 + mi * 16 + quad * 4 + r;
        out[(((size_t)b * 256 + o) * 64 + h) * 64 + w] =
            acc[mi][tn][r] + bias[o];
      }
    }
}

extern "C" void kernel_launch(void* const* d_in, const int* in_sizes, int n_in,
                              void* d_out, int out_size, void* d_ws,
                              size_t ws_size, hipStream_t stream) {
  (void)in_sizes; (void)n_in; (void)out_size; (void)ws_size;
  const float* x        = (const float*)d_in[0];  // (4,256,64,64)
  const float* offset_w = (const float*)d_in[1];  // (18,256,3,3)
  const float* offset_b = (const float*)d_in[2];  // (18,)
  const float* deform_w = (const float*)d_in[3];  // (256,256,3,3)
  const float* deform_b = (const float*)d_in[4];  // (256,)
  float* out = (float*)d_out;

  float* off_buf = (float*)d_ws;                                // 294912 f
  unsigned short* wfrag = (unsigned short*)(off_buf + 294912);  // 589824 bf16
  unsigned short* wfragA = wfrag + 589824;                      // 73728 bf16

  hipMemsetAsync(off_buf, 0, 294912 * sizeof(float), stream);
  prep_kernel<<<324, 256, 0, stream>>>(deform_w, offset_w, wfrag, wfragA);
  offset_conv_mfma<<<dim3(64, 4, 2), 256, 0, stream>>>(x, wfragA, off_buf);
  deform_kernel<<<dim3(128, 4), 256, 0, stream>>>(x, off_buf, offset_b, wfrag,
                                                  deform_b, out);
  hipMemcpyAsync(out + 4194304, deform_w, 589824 * sizeof(float),
                 hipMemcpyDeviceToDevice, stream);
}